// Round 5
// baseline (168.994 us; speedup 1.0000x reference)
//
#include <hip/hip_runtime.h>
#include <math.h>

// Problem constants (match reference)
constexpr int B_  = 4;
constexpr int N_  = 4096;
constexpr int M_  = 4096;
constexpr int H_  = 8;
constexpr int D_  = 64;
constexpr int DV_ = 64;
constexpr int BH  = B_ * H_;     // 32
constexpr int RSTR = H_ * D_;    // 512 floats: row stride of q/k/v/out

// Phase 1: 1024 blocks, 8x8 register tile per thread, 4-way m-split (1 wave each)
constexpr int CH     = 32;        // M-chunks per (b,h)
constexpr int ROWS   = M_ / CH;   // 128 rows per block
constexpr int TM     = 32;        // rows per LDS tile
constexpr int NTILES = ROWS / TM; // 4

// Phase 2: 1024 blocks of 128 threads; 8 rows x 8 cols per thread, no d-split
constexpr int NT2 = 128;          // q rows per block
constexpr int QST = D_ + 4;       // 68: row stride -> consecutive rows shift bank-quad by 4

__device__ __forceinline__ float elu1(float x) {
    // elu(x)+1 = x+1 for x>0, exp(x) for x<=0
    return x > 0.f ? x + 1.f : __expf(x);
}

// kv[d][e] = sum_m elu1(k[m][d]) * v[m][e],  z[d] = sum_m elu1(k[m][d])   (per chunk)
__global__ __launch_bounds__(256) void kv_part_kernel(
    const float* __restrict__ k, const float* __restrict__ v,
    float* __restrict__ kv_out, float* __restrict__ z_out, const int atomic_mode)
{
    __shared__ float k_s[2][TM][D_];   // 16 KB (merge buffer A after loop)
    __shared__ float v_s[2][TM][DV_];  // 16 KB (merge buffer B after loop)
    __shared__ float zbuf[4][D_];      // per-wave z partials

    const int bx    = blockIdx.x;
    const int chunk = bx & (CH - 1);
    const int bh    = bx >> 5;           // CH == 32
    const int b     = bh / H_;
    const int h     = bh % H_;
    const int tid   = threadIdx.x;

    const int lr  = tid >> 4;   // 0..15 : loader row (also handles lr+16)
    const int ld4 = tid & 15;   // 0..15 : float4 within row

    const size_t base = ((size_t)b * M_ * H_ + h) * D_ + (size_t)ld4 * 4;
    const float* kp = k + base + (size_t)(chunk * ROWS + lr) * RSTR;
    const float* vp = v + base + (size_t)(chunk * ROWS + lr) * RSTR;

    // prefetch tile 0 (rows lr, lr+16)
    float4 kf0 = *(const float4*)kp;
    float4 kf1 = *(const float4*)(kp + (size_t)16 * RSTR);
    float4 vf0 = *(const float4*)vp;
    float4 vf1 = *(const float4*)(vp + (size_t)16 * RSTR);

    const int g   = tid >> 6;   // wave id == m-subgroup (8 rows per tile)
    const int pos = tid & 63;
    const int pd  = pos >> 3;   // 0..7 : d-block (8 d's)
    const int pe  = pos & 7;    // 0..7 : e-block (8 e's)

    float acc[8][8] = {};
    float zacc[8] = {};          // z partial for this thread's 8 d's (redundant x8 over pe)

    for (int t = 0; t < NTILES; ++t) {
        const int cur = t & 1;
        float4 ke0, ke1;
        ke0.x = elu1(kf0.x); ke0.y = elu1(kf0.y); ke0.z = elu1(kf0.z); ke0.w = elu1(kf0.w);
        ke1.x = elu1(kf1.x); ke1.y = elu1(kf1.y); ke1.z = elu1(kf1.z); ke1.w = elu1(kf1.w);
        *(float4*)&k_s[cur][lr][ld4 * 4]      = ke0;
        *(float4*)&k_s[cur][lr + 16][ld4 * 4] = ke1;
        *(float4*)&v_s[cur][lr][ld4 * 4]      = vf0;
        *(float4*)&v_s[cur][lr + 16][ld4 * 4] = vf1;
        if (t + 1 < NTILES) {               // next tile's loads fly during compute
            kp += (size_t)TM * RSTR; vp += (size_t)TM * RSTR;
            kf0 = *(const float4*)kp;
            kf1 = *(const float4*)(kp + (size_t)16 * RSTR);
            vf0 = *(const float4*)vp;
            vf1 = *(const float4*)(vp + (size_t)16 * RSTR);
        }
        __syncthreads();                    // publish buf[cur]

        #pragma unroll
        for (int r8 = 0; r8 < 8; ++r8) {
            const int r = g * 8 + r8;       // this wave's rows
            const float4 ka = *(const float4*)&k_s[cur][r][pd * 8];       // 2-way, free
            const float4 kb = *(const float4*)&k_s[cur][r][pd * 8 + 4];
            const float4 va = *(const float4*)&v_s[cur][r][pe * 8];
            const float4 vb = *(const float4*)&v_s[cur][r][pe * 8 + 4];
            const float kd[8] = {ka.x, ka.y, ka.z, ka.w, kb.x, kb.y, kb.z, kb.w};
            const float vv[8] = {va.x, va.y, va.z, va.w, vb.x, vb.y, vb.z, vb.w};
            #pragma unroll
            for (int i = 0; i < 8; ++i) {
                zacc[i] += kd[i];           // z from registers: no extra LDS read
                #pragma unroll
                for (int j = 0; j < 8; ++j)
                    acc[i][j] += kd[i] * vv[j];
            }
        }
    }

    // ---- merge the 4 m-subgroups in LDS (reuse tile space) ----
    __syncthreads();                        // all compute done; tiles reusable
    float* A  = &k_s[0][0][0];              // 4096 floats
    float* Bb = &v_s[0][0][0];              // 4096 floats

    if (pe == 0) {                          // one writer per (g, pd): zbuf[g][pd*8+i]
        #pragma unroll
        for (int i = 0; i < 8; ++i) zbuf[g][pd * 8 + i] = zacc[i];
    }
    if (g == 0 || g == 2) {                 // P1: write
        float* dst = (g == 0) ? A : Bb;
        #pragma unroll
        for (int i = 0; i < 8; ++i) {
            float4 r0, r1;
            r0.x = acc[i][0]; r0.y = acc[i][1]; r0.z = acc[i][2]; r0.w = acc[i][3];
            r1.x = acc[i][4]; r1.y = acc[i][5]; r1.z = acc[i][6]; r1.w = acc[i][7];
            *(float4*)&dst[(pd * 8 + i) * DV_ + pe * 8]     = r0;
            *(float4*)&dst[(pd * 8 + i) * DV_ + pe * 8 + 4] = r1;
        }
    }
    __syncthreads();
    if (g == 1 || g == 3) {                 // P2: add
        float* dst = (g == 1) ? A : Bb;
        #pragma unroll
        for (int i = 0; i < 8; ++i) {
            float4* p0 = (float4*)&dst[(pd * 8 + i) * DV_ + pe * 8];
            float4* p1 = (float4*)&dst[(pd * 8 + i) * DV_ + pe * 8 + 4];
            float4 r0 = *p0, r1 = *p1;
            r0.x += acc[i][0]; r0.y += acc[i][1]; r0.z += acc[i][2]; r0.w += acc[i][3];
            r1.x += acc[i][4]; r1.y += acc[i][5]; r1.z += acc[i][6]; r1.w += acc[i][7];
            *p0 = r0; *p1 = r1;
        }
    }
    __syncthreads();
    // P3: all 256 threads combine A+B and write out
    if (!atomic_mode) {
        float* kvp = kv_out + ((size_t)bh * CH + chunk) * (D_ * DV_);
        #pragma unroll
        for (int j2 = 0; j2 < 4; ++j2) {
            const int idx = tid + j2 * 256;          // float4 index, 1024 total
            float4 a4 = ((const float4*)A)[idx];
            const float4 b4 = ((const float4*)Bb)[idx];
            a4.x += b4.x; a4.y += b4.y; a4.z += b4.z; a4.w += b4.w;
            ((float4*)kvp)[idx] = a4;
        }
        if (tid < D_)
            z_out[((size_t)bh * CH + chunk) * D_ + tid] =
                zbuf[0][tid] + zbuf[1][tid] + zbuf[2][tid] + zbuf[3][tid];
    } else {
        float* kvp = kv_out + (size_t)bh * D_ * DV_;
        #pragma unroll
        for (int j2 = 0; j2 < 4; ++j2) {
            const int idx = tid + j2 * 256;
            const float4 a4 = ((const float4*)A)[idx];
            const float4 b4 = ((const float4*)Bb)[idx];
            atomicAdd(&kvp[idx * 4 + 0], a4.x + b4.x);
            atomicAdd(&kvp[idx * 4 + 1], a4.y + b4.y);
            atomicAdd(&kvp[idx * 4 + 2], a4.z + b4.z);
            atomicAdd(&kvp[idx * 4 + 3], a4.w + b4.w);
        }
        if (tid < D_)
            atomicAdd(&z_out[bh * D_ + tid],
                      zbuf[0][tid] + zbuf[1][tid] + zbuf[2][tid] + zbuf[3][tid]);
    }
}

// Sum CH partials. One float per thread, fully coalesced.
__global__ __launch_bounds__(256) void kv_sum_kernel(
    const float* __restrict__ kv_part, const float* __restrict__ z_part,
    float* __restrict__ kv, float* __restrict__ z)
{
    const int gid = blockIdx.x * 256 + threadIdx.x;
    if (gid < BH * D_ * DV_) {
        const int bh = gid >> 12;            // /4096
        const int within = gid & 4095;
        const float* src = kv_part + ((size_t)bh * CH) * (D_ * DV_) + within;
        float a = 0.f;
        #pragma unroll 8
        for (int c = 0; c < CH; ++c) a += src[(size_t)c * (D_ * DV_)];
        kv[gid] = a;
    } else if (gid < BH * D_ * DV_ + BH * D_) {
        const int zi = gid - BH * D_ * DV_;
        const int bh = zi >> 6;
        const int within = zi & 63;
        const float* src = z_part + ((size_t)bh * CH) * D_ + within;
        float a = 0.f;
        #pragma unroll 8
        for (int c = 0; c < CH; ++c) a += src[(size_t)c * D_];
        z[zi] = a;
    }
}

// out[n][e] = (sum_d elu1(q[n][d]) * kv[d][e]) / (sum_d elu1(q[n][d]) * z[d] + 1e-6)
// 128 threads: thread (pn=tid>>3 in 0..15, pe=tid&7) owns rows {pn+16*i} x cols [pe*8, pe*8+8).
// No d-split, no merge phase; nrm computed redundantly per pe (8 FMA/d4 — free).
__global__ __launch_bounds__(128) void out_kernel(
    const float* __restrict__ q, const float* __restrict__ kv,
    const float* __restrict__ z, float* __restrict__ out)
{
    __shared__ float kv_s[D_][DV_];       // 16 KB
    __shared__ float q_s[NT2][QST];       // 34 KB; stride 68: row i -> bank-quad 4i (conflict-free column reads)
    __shared__ float z_s[D_];

    const int bx  = blockIdx.x;
    const int nt  = bx & (N_ / NT2 - 1);  // 32 tiles per bh
    const int bh  = bx >> 5;
    const int b   = bh / H_;
    const int h   = bh % H_;
    const int tid = threadIdx.x;

    {   // kv tile: 1024 float4 over 128 threads
        const float4* src = (const float4*)(kv + (size_t)bh * D_ * DV_);
        float4* dst = (float4*)&kv_s[0][0];
        #pragma unroll
        for (int i = 0; i < 8; ++i) dst[tid + i * 128] = src[tid + i * 128];
    }
    if (tid < D_ / 4) ((float4*)z_s)[tid] = ((const float4*)(z + bh * D_))[tid];

    {   // q tile: 128 rows x 64 with elu; 2 float4 per row per thread, 8 rows per pass
        const int lr = tid >> 3;          // 0..15
        const int c  = tid & 7;           // 0..7 : float4 col (and c+8)
        const float* qb = q + ((size_t)(b * N_ + nt * NT2) * H_ + h) * D_;
        #pragma unroll
        for (int p = 0; p < NT2 / 16; ++p) {
            const int r = p * 16 + lr;
            const float4 qf0 = *(const float4*)(qb + (size_t)r * RSTR + c * 4);
            const float4 qf1 = *(const float4*)(qb + (size_t)r * RSTR + (c + 8) * 4);
            float4 e0, e1;
            e0.x = elu1(qf0.x); e0.y = elu1(qf0.y); e0.z = elu1(qf0.z); e0.w = elu1(qf0.w);
            e1.x = elu1(qf1.x); e1.y = elu1(qf1.y); e1.z = elu1(qf1.z); e1.w = elu1(qf1.w);
            *(float4*)&q_s[r][c * 4]       = e0;
            *(float4*)&q_s[r][(c + 8) * 4] = e1;
        }
    }
    __syncthreads();

    const int pn = tid >> 3;   // 0..15 : row group (rows pn + 16*i)
    const int pe = tid & 7;    // 0..7  : e-block (8 cols)

    float acc[8][8] = {};
    float nrm[8] = {};

    #pragma unroll 2
    for (int d4 = 0; d4 < 16; ++d4) {
        const float4 z4 = *(const float4*)&z_s[d4 * 4];
        float qv[8][4];
        #pragma unroll
        for (int i = 0; i < 8; ++i) {
            const float4 t = *(const float4*)&q_s[pn + 16 * i][d4 * 4];  // conflict-free
            qv[i][0] = t.x; qv[i][1] = t.y; qv[i][2] = t.z; qv[i][3] = t.w;
            nrm[i] += t.x * z4.x + t.y * z4.y + t.z * z4.z + t.w * z4.w;
        }
        #pragma unroll
        for (int dd = 0; dd < 4; ++dd) {
            const int d = d4 * 4 + dd;
            const float4 kva = *(const float4*)&kv_s[d][pe * 8];      // 2-way, free
            const float4 kvb = *(const float4*)&kv_s[d][pe * 8 + 4];
            const float kvv[8] = {kva.x, kva.y, kva.z, kva.w, kvb.x, kvb.y, kvb.z, kvb.w};
            #pragma unroll
            for (int i = 0; i < 8; ++i) {
                const float qd = qv[i][dd];
                #pragma unroll
                for (int j = 0; j < 8; ++j)
                    acc[i][j] += qd * kvv[j];
            }
        }
    }

    float* obase = out + ((size_t)(b * N_ + nt * NT2) * H_ + h) * DV_;
    #pragma unroll
    for (int i = 0; i < 8; ++i) {
        const int r = pn + 16 * i;
        const float inv = 1.f / (nrm[i] + 1e-6f);
        float4 o0, o1;
        o0.x = acc[i][0] * inv; o0.y = acc[i][1] * inv;
        o0.z = acc[i][2] * inv; o0.w = acc[i][3] * inv;
        o1.x = acc[i][4] * inv; o1.y = acc[i][5] * inv;
        o1.z = acc[i][6] * inv; o1.w = acc[i][7] * inv;
        *(float4*)(obase + (size_t)r * RSTR + pe * 8)     = o0;
        *(float4*)(obase + (size_t)r * RSTR + pe * 8 + 4) = o1;
    }
}

extern "C" void kernel_launch(void* const* d_in, const int* in_sizes, int n_in,
                              void* d_out, int out_size, void* d_ws, size_t ws_size,
                              hipStream_t stream) {
    const float* q = (const float*)d_in[0];
    const float* k = (const float*)d_in[1];
    const float* v = (const float*)d_in[2];
    float* out = (float*)d_out;

    const size_t kvp_elems = (size_t)CH * BH * D_ * DV_;  // 4,194,304
    const size_t zp_elems  = (size_t)CH * BH * D_;        //    65,536
    const size_t kv_elems  = (size_t)BH * D_ * DV_;       //   131,072
    const size_t z_elems   = (size_t)BH * D_;             //     2,048
    const size_t need = (kvp_elems + zp_elems + kv_elems + z_elems) * sizeof(float);

    if (ws_size >= need) {
        float* kv_part = (float*)d_ws;
        float* z_part  = kv_part + kvp_elems;
        float* kvb     = z_part + zp_elems;
        float* zb      = kvb + kv_elems;
        kv_part_kernel<<<BH * CH, 256, 0, stream>>>(k, v, kv_part, z_part, 0);
        kv_sum_kernel<<<(int)((kv_elems + z_elems + 255) / 256), 256, 0, stream>>>(
            kv_part, z_part, kvb, zb);
        out_kernel<<<BH * (N_ / NT2), 128, 0, stream>>>(q, kvb, zb, out);
    } else {
        float* kvb = (float*)d_ws;
        float* zb  = kvb + kv_elems;
        hipMemsetAsync(d_ws, 0, (kv_elems + z_elems) * sizeof(float), stream);
        kv_part_kernel<<<BH * CH, 256, 0, stream>>>(k, v, kvb, zb, 1);
        out_kernel<<<BH * (N_ / NT2), 128, 0, stream>>>(q, kvb, zb, out);
    }
}

// Round 6
// 159.989 us; speedup vs baseline: 1.0563x; 1.0563x over previous
//
#include <hip/hip_runtime.h>
#include <math.h>

// Problem constants (match reference)
constexpr int B_  = 4;
constexpr int N_  = 4096;
constexpr int M_  = 4096;
constexpr int H_  = 8;
constexpr int D_  = 64;
constexpr int DV_ = 64;
constexpr int BH  = B_ * H_;     // 32
constexpr int RSTR = H_ * D_;    // 512 floats: row stride of q/k/v/out

// Phase 1: 1024 blocks, 8x8 register tile per thread, 4-way m-split (1 wave each)
constexpr int CH     = 32;        // M-chunks per (b,h)
constexpr int ROWS   = M_ / CH;   // 128 rows per block
constexpr int TM     = 32;        // rows per LDS tile
constexpr int NTILES = ROWS / TM; // 4

// Phase 2: 1024 blocks of 256 threads (4 waves); 4 rows x 8 cols per thread
constexpr int NT2 = 128;          // q rows per block
constexpr int QST = D_ + 4;       // 68: row stride -> row i at bank-quad 4i (conflict-free column reads)

__device__ __forceinline__ float elu1(float x) {
    // elu(x)+1 = x+1 for x>0, exp(x) for x<=0
    return x > 0.f ? x + 1.f : __expf(x);
}

// kv[d][e] = sum_m elu1(k[m][d]) * v[m][e],  z[d] = sum_m elu1(k[m][d])   (per chunk)
__global__ __launch_bounds__(256) void kv_part_kernel(
    const float* __restrict__ k, const float* __restrict__ v,
    float* __restrict__ kv_out, float* __restrict__ z_out, const int atomic_mode)
{
    __shared__ float k_s[2][TM][D_];   // 16 KB (merge buffer A after loop)
    __shared__ float v_s[2][TM][DV_];  // 16 KB (merge buffer B after loop)
    __shared__ float zbuf[4][D_];      // per-wave z partials

    const int bx    = blockIdx.x;
    const int chunk = bx & (CH - 1);
    const int bh    = bx >> 5;           // CH == 32
    const int b     = bh / H_;
    const int h     = bh % H_;
    const int tid   = threadIdx.x;

    const int lr  = tid >> 4;   // 0..15 : loader row (also handles lr+16)
    const int ld4 = tid & 15;   // 0..15 : float4 within row

    const size_t base = ((size_t)b * M_ * H_ + h) * D_ + (size_t)ld4 * 4;
    const float* kp = k + base + (size_t)(chunk * ROWS + lr) * RSTR;
    const float* vp = v + base + (size_t)(chunk * ROWS + lr) * RSTR;

    // prefetch tile 0 (rows lr, lr+16)
    float4 kf0 = *(const float4*)kp;
    float4 kf1 = *(const float4*)(kp + (size_t)16 * RSTR);
    float4 vf0 = *(const float4*)vp;
    float4 vf1 = *(const float4*)(vp + (size_t)16 * RSTR);

    const int g   = tid >> 6;   // wave id == m-subgroup (8 rows per tile)
    const int pos = tid & 63;
    const int pd  = pos >> 3;   // 0..7 : d-block (8 d's)
    const int pe  = pos & 7;    // 0..7 : e-block (8 e's)

    float acc[8][8] = {};
    float zacc[8] = {};          // z partial for this thread's 8 d's (redundant x8 over pe)

    for (int t = 0; t < NTILES; ++t) {
        const int cur = t & 1;
        float4 ke0, ke1;
        ke0.x = elu1(kf0.x); ke0.y = elu1(kf0.y); ke0.z = elu1(kf0.z); ke0.w = elu1(kf0.w);
        ke1.x = elu1(kf1.x); ke1.y = elu1(kf1.y); ke1.z = elu1(kf1.z); ke1.w = elu1(kf1.w);
        *(float4*)&k_s[cur][lr][ld4 * 4]      = ke0;
        *(float4*)&k_s[cur][lr + 16][ld4 * 4] = ke1;
        *(float4*)&v_s[cur][lr][ld4 * 4]      = vf0;
        *(float4*)&v_s[cur][lr + 16][ld4 * 4] = vf1;
        if (t + 1 < NTILES) {               // next tile's loads fly during compute
            kp += (size_t)TM * RSTR; vp += (size_t)TM * RSTR;
            kf0 = *(const float4*)kp;
            kf1 = *(const float4*)(kp + (size_t)16 * RSTR);
            vf0 = *(const float4*)vp;
            vf1 = *(const float4*)(vp + (size_t)16 * RSTR);
        }
        __syncthreads();                    // publish buf[cur]

        #pragma unroll
        for (int r8 = 0; r8 < 8; ++r8) {
            const int r = g * 8 + r8;       // this wave's rows
            const float4 ka = *(const float4*)&k_s[cur][r][pd * 8];       // 2-way, free
            const float4 kb = *(const float4*)&k_s[cur][r][pd * 8 + 4];
            const float4 va = *(const float4*)&v_s[cur][r][pe * 8];
            const float4 vb = *(const float4*)&v_s[cur][r][pe * 8 + 4];
            const float kd[8] = {ka.x, ka.y, ka.z, ka.w, kb.x, kb.y, kb.z, kb.w};
            const float vv[8] = {va.x, va.y, va.z, va.w, vb.x, vb.y, vb.z, vb.w};
            #pragma unroll
            for (int i = 0; i < 8; ++i) {
                zacc[i] += kd[i];           // z from registers: no extra LDS read
                #pragma unroll
                for (int j = 0; j < 8; ++j)
                    acc[i][j] += kd[i] * vv[j];
            }
        }
    }

    // ---- merge the 4 m-subgroups in LDS (reuse tile space) ----
    __syncthreads();                        // all compute done; tiles reusable
    float* A  = &k_s[0][0][0];              // 4096 floats
    float* Bb = &v_s[0][0][0];              // 4096 floats

    if (pe == 0) {                          // one writer per (g, pd): zbuf[g][pd*8+i]
        #pragma unroll
        for (int i = 0; i < 8; ++i) zbuf[g][pd * 8 + i] = zacc[i];
    }
    if (g == 0 || g == 2) {                 // P1: write
        float* dst = (g == 0) ? A : Bb;
        #pragma unroll
        for (int i = 0; i < 8; ++i) {
            float4 r0, r1;
            r0.x = acc[i][0]; r0.y = acc[i][1]; r0.z = acc[i][2]; r0.w = acc[i][3];
            r1.x = acc[i][4]; r1.y = acc[i][5]; r1.z = acc[i][6]; r1.w = acc[i][7];
            *(float4*)&dst[(pd * 8 + i) * DV_ + pe * 8]     = r0;
            *(float4*)&dst[(pd * 8 + i) * DV_ + pe * 8 + 4] = r1;
        }
    }
    __syncthreads();
    if (g == 1 || g == 3) {                 // P2: add
        float* dst = (g == 1) ? A : Bb;
        #pragma unroll
        for (int i = 0; i < 8; ++i) {
            float4* p0 = (float4*)&dst[(pd * 8 + i) * DV_ + pe * 8];
            float4* p1 = (float4*)&dst[(pd * 8 + i) * DV_ + pe * 8 + 4];
            float4 r0 = *p0, r1 = *p1;
            r0.x += acc[i][0]; r0.y += acc[i][1]; r0.z += acc[i][2]; r0.w += acc[i][3];
            r1.x += acc[i][4]; r1.y += acc[i][5]; r1.z += acc[i][6]; r1.w += acc[i][7];
            *p0 = r0; *p1 = r1;
        }
    }
    __syncthreads();
    // P3: all 256 threads combine A+B and write out
    if (!atomic_mode) {
        float* kvp = kv_out + ((size_t)bh * CH + chunk) * (D_ * DV_);
        #pragma unroll
        for (int j2 = 0; j2 < 4; ++j2) {
            const int idx = tid + j2 * 256;          // float4 index, 1024 total
            float4 a4 = ((const float4*)A)[idx];
            const float4 b4 = ((const float4*)Bb)[idx];
            a4.x += b4.x; a4.y += b4.y; a4.z += b4.z; a4.w += b4.w;
            ((float4*)kvp)[idx] = a4;
        }
        if (tid < D_)
            z_out[((size_t)bh * CH + chunk) * D_ + tid] =
                zbuf[0][tid] + zbuf[1][tid] + zbuf[2][tid] + zbuf[3][tid];
    } else {
        float* kvp = kv_out + (size_t)bh * D_ * DV_;
        #pragma unroll
        for (int j2 = 0; j2 < 4; ++j2) {
            const int idx = tid + j2 * 256;
            const float4 a4 = ((const float4*)A)[idx];
            const float4 b4 = ((const float4*)Bb)[idx];
            atomicAdd(&kvp[idx * 4 + 0], a4.x + b4.x);
            atomicAdd(&kvp[idx * 4 + 1], a4.y + b4.y);
            atomicAdd(&kvp[idx * 4 + 2], a4.z + b4.z);
            atomicAdd(&kvp[idx * 4 + 3], a4.w + b4.w);
        }
        if (tid < D_)
            atomicAdd(&z_out[bh * D_ + tid],
                      zbuf[0][tid] + zbuf[1][tid] + zbuf[2][tid] + zbuf[3][tid]);
    }
}

// Sum CH partials, float4 per thread. 520 blocks x 64 threads = 33280 float4s
// (32768 kv + 512 z) -> covers all 256 CUs, fully coalesced (1KB/wave/step).
__global__ __launch_bounds__(64) void kv_sum_kernel(
    const float4* __restrict__ kv_part, const float4* __restrict__ z_part,
    float4* __restrict__ kv, float4* __restrict__ z)
{
    const int gid = blockIdx.x * 64 + threadIdx.x;
    if (gid < BH * D_ * DV_ / 4) {
        const int bh = gid >> 10;            // 1024 float4 per bh
        const int within = gid & 1023;
        const float4* src = kv_part + ((size_t)bh * CH) * 1024 + within;
        float4 a = {0.f, 0.f, 0.f, 0.f};
        #pragma unroll 8
        for (int c = 0; c < CH; ++c) {
            const float4 p = src[(size_t)c * 1024];
            a.x += p.x; a.y += p.y; a.z += p.z; a.w += p.w;
        }
        kv[gid] = a;
    } else {
        const int zi = gid - BH * D_ * DV_ / 4;   // [0, 512)
        const int bh = zi >> 4;                   // 16 float4 per bh
        const int within = zi & 15;
        const float4* src = z_part + ((size_t)bh * CH) * 16 + within;
        float4 a = {0.f, 0.f, 0.f, 0.f};
        #pragma unroll 8
        for (int c = 0; c < CH; ++c) {
            const float4 p = src[(size_t)c * 16];
            a.x += p.x; a.y += p.y; a.z += p.z; a.w += p.w;
        }
        z[zi] = a;
    }
}

// out[n][e] = (sum_d elu1(q[n][d]) * kv[d][e]) / (sum_d elu1(q[n][d]) * z[d] + 1e-6)
// 256 threads (4 waves): thread (pn=tid>>3 in 0..31, pe=tid&7) owns rows {pn+32i, i<4}
// x cols [pe*8, pe*8+8). nrm redundant per pe (free). 3 blocks/CU -> 12 waves/CU.
__global__ __launch_bounds__(256) void out_kernel(
    const float* __restrict__ q, const float* __restrict__ kv,
    const float* __restrict__ z, float* __restrict__ out)
{
    __shared__ float kv_s[D_][DV_];       // 16 KB
    __shared__ float q_s[NT2][QST];       // 34 KB
    __shared__ float z_s[D_];

    const int bx  = blockIdx.x;
    const int nt  = bx & (N_ / NT2 - 1);  // 32 tiles per bh
    const int bh  = bx >> 5;
    const int b   = bh / H_;
    const int h   = bh % H_;
    const int tid = threadIdx.x;

    {   // kv tile: 1024 float4 over 256 threads
        const float4* src = (const float4*)(kv + (size_t)bh * D_ * DV_);
        float4* dst = (float4*)&kv_s[0][0];
        #pragma unroll
        for (int i = 0; i < 4; ++i) dst[tid + i * 256] = src[tid + i * 256];
    }
    if (tid < D_ / 4) ((float4*)z_s)[tid] = ((const float4*)(z + bh * D_))[tid];

    {   // q tile: 128 rows x 64 with elu; 8 float4 per thread (one per 16-row group)
        const int lr = tid >> 4;          // 0..15
        const int c  = tid & 15;          // 0..15 : float4 col
        const float* qb = q + ((size_t)(b * N_ + nt * NT2) * H_ + h) * D_;
        #pragma unroll
        for (int p = 0; p < NT2 / 16; ++p) {
            const int r = p * 16 + lr;
            const float4 qf = *(const float4*)(qb + (size_t)r * RSTR + c * 4);
            float4 e;
            e.x = elu1(qf.x); e.y = elu1(qf.y); e.z = elu1(qf.z); e.w = elu1(qf.w);
            *(float4*)&q_s[r][c * 4] = e;
        }
    }
    __syncthreads();

    const int pn = tid >> 3;   // 0..31 : row group (rows pn + 32*i)
    const int pe = tid & 7;    // 0..7  : e-block (8 cols)

    float acc[4][8] = {};
    float nrm[4] = {};

    #pragma unroll 4
    for (int d4 = 0; d4 < 16; ++d4) {
        const float4 z4 = *(const float4*)&z_s[d4 * 4];
        float qv[4][4];
        #pragma unroll
        for (int i = 0; i < 4; ++i) {
            const float4 t = *(const float4*)&q_s[pn + 32 * i][d4 * 4];  // conflict-free
            qv[i][0] = t.x; qv[i][1] = t.y; qv[i][2] = t.z; qv[i][3] = t.w;
            nrm[i] += t.x * z4.x + t.y * z4.y + t.z * z4.z + t.w * z4.w;
        }
        #pragma unroll
        for (int dd = 0; dd < 4; ++dd) {
            const int d = d4 * 4 + dd;
            const float4 kva = *(const float4*)&kv_s[d][pe * 8];      // 2-way, free
            const float4 kvb = *(const float4*)&kv_s[d][pe * 8 + 4];
            const float kvv[8] = {kva.x, kva.y, kva.z, kva.w, kvb.x, kvb.y, kvb.z, kvb.w};
            #pragma unroll
            for (int i = 0; i < 4; ++i) {
                const float qd = qv[i][dd];
                #pragma unroll
                for (int j = 0; j < 8; ++j)
                    acc[i][j] += qd * kvv[j];
            }
        }
    }

    float* obase = out + ((size_t)(b * N_ + nt * NT2) * H_ + h) * DV_;
    #pragma unroll
    for (int i = 0; i < 4; ++i) {
        const int r = pn + 32 * i;
        const float inv = 1.f / (nrm[i] + 1e-6f);
        float4 o0, o1;
        o0.x = acc[i][0] * inv; o0.y = acc[i][1] * inv;
        o0.z = acc[i][2] * inv; o0.w = acc[i][3] * inv;
        o1.x = acc[i][4] * inv; o1.y = acc[i][5] * inv;
        o1.z = acc[i][6] * inv; o1.w = acc[i][7] * inv;
        *(float4*)(obase + (size_t)r * RSTR + pe * 8)     = o0;
        *(float4*)(obase + (size_t)r * RSTR + pe * 8 + 4) = o1;
    }
}

extern "C" void kernel_launch(void* const* d_in, const int* in_sizes, int n_in,
                              void* d_out, int out_size, void* d_ws, size_t ws_size,
                              hipStream_t stream) {
    const float* q = (const float*)d_in[0];
    const float* k = (const float*)d_in[1];
    const float* v = (const float*)d_in[2];
    float* out = (float*)d_out;

    const size_t kvp_elems = (size_t)CH * BH * D_ * DV_;  // 4,194,304
    const size_t zp_elems  = (size_t)CH * BH * D_;        //    65,536
    const size_t kv_elems  = (size_t)BH * D_ * DV_;       //   131,072
    const size_t z_elems   = (size_t)BH * D_;             //     2,048
    const size_t need = (kvp_elems + zp_elems + kv_elems + z_elems) * sizeof(float);

    if (ws_size >= need) {
        float* kv_part = (float*)d_ws;
        float* z_part  = kv_part + kvp_elems;
        float* kvb     = z_part + zp_elems;
        float* zb      = kvb + kv_elems;
        kv_part_kernel<<<BH * CH, 256, 0, stream>>>(k, v, kv_part, z_part, 0);
        kv_sum_kernel<<<520, 64, 0, stream>>>((const float4*)kv_part, (const float4*)z_part,
                                              (float4*)kvb, (float4*)zb);
        out_kernel<<<BH * (N_ / NT2), 256, 0, stream>>>(q, kvb, zb, out);
    } else {
        float* kvb = (float*)d_ws;
        float* zb  = kvb + kv_elems;
        hipMemsetAsync(d_ws, 0, (kv_elems + z_elems) * sizeof(float), stream);
        kv_part_kernel<<<BH * CH, 256, 0, stream>>>(k, v, kvb, zb, 1);
        out_kernel<<<BH * (N_ / NT2), 256, 0, stream>>>(q, kvb, zb, out);
    }
}